// Round 12
// baseline (10434.871 us; speedup 1.0000x reference)
//
#include <hip/hip_runtime.h>
#include <stdint.h>

// Problem dims (fixed)
#define B_  256
#define T_  1024
#define D_  128
#define H_  512
#define G4_ 2048            // 4*H
#define BT_ (B_ * T_)

// Persistent-LSTM partitioning: 16 batch groups x 8 col-WGs = 128 WGs
#define NG_  16             // batch groups (16 rows each)
#define NCW_ 8              // col-WGs per group (64 h-cols each)

typedef unsigned short u16;
typedef __attribute__((ext_vector_type(8))) short    bf16x8;  // 8 bf16 in 4 VGPRs
typedef __attribute__((ext_vector_type(8))) u16      u16x8;
typedef __attribute__((ext_vector_type(4))) float    f32x4;
typedef __attribute__((ext_vector_type(4))) uint32_t u32x4;

static __device__ __forceinline__ u16 f2bf(float f) {
  uint32_t u = __builtin_bit_cast(uint32_t, f);
  u += 0x7FFFu + ((u >> 16) & 1u);   // RNE
  return (u16)(u >> 16);
}

static __device__ __forceinline__ u16x8 pack8(float4 a, float4 b) {
  u16x8 p;
  p[0] = f2bf(a.x); p[1] = f2bf(a.y); p[2] = f2bf(a.z); p[3] = f2bf(a.w);
  p[4] = f2bf(b.x); p[5] = f2bf(b.y); p[6] = f2bf(b.z); p[7] = f2bf(b.w);
  return p;
}

static __device__ __forceinline__ float fast_sig(float x) {
  return 1.f / (1.f + __expf(-x));
}
static __device__ __forceinline__ float fast_tanh(float x) {
  return 1.f - 2.f / (__expf(2.f * x) + 1.f);
}

// raw barrier: order LDS only; never drains vmcnt (publish stores float)
#define BAR_LDS() asm volatile("s_waitcnt lgkmcnt(0)\n\ts_barrier" ::: "memory")

// ---------------------------------------------------------------------------
// prep: bf16 weight copies, bias sum, zero exchange buffer and out[:,0,:]
// ---------------------------------------------------------------------------
__global__ void prep_kernel(const float* __restrict__ Whh, const float* __restrict__ Wih,
                            const float* __restrict__ w1,  const float* __restrict__ w2,
                            const float* __restrict__ b_ih, const float* __restrict__ b_hh,
                            u16* __restrict__ Whh_bf, u16* __restrict__ Wih_bf,
                            u16* __restrict__ w1y_bf, u16* __restrict__ w2_bf,
                            float* __restrict__ w1s, float* __restrict__ bsum,
                            uint32_t* __restrict__ xch32, float* __restrict__ Yd) {
  const int idx = blockIdx.x * blockDim.x + threadIdx.x;
  if (idx < G4_ * H_) Whh_bf[idx] = f2bf(Whh[idx]);
  if (idx < G4_ * D_) Wih_bf[idx] = f2bf(Wih[idx]);
  if (idx < H_ * H_) {
    const int n = idx >> 9, k = idx & 511;
    w1y_bf[idx] = f2bf(w1[n * 513 + 1 + k]);                 // w1[:,1:]
    w2_bf[idx]  = f2bf(w2[idx]);
  }
  if (idx < H_)  w1s[idx]  = w1[idx * 513];                  // w1[:,0]
  if (idx < G4_) bsum[idx] = b_ih[idx] + b_hh[idx];
  if (idx < 2 * B_ * H_) xch32[idx] = 0;                     // tag 0 (both parities)
  if (idx < B_ * H_) {
    const int b = idx >> 9, h = idx & 511;
    Yd[(size_t)b * T_ * H_ + h] = 0.f;                       // out[b,0,:] = h_0 = 0
  }
}

// x fp32 -> bf16 pre-conversion
__global__ void xconv_kernel(const float* __restrict__ x, u16* __restrict__ xbf) {
  const size_t i = ((size_t)blockIdx.x * blockDim.x + threadIdx.x) * 16;
  const float4* s4 = (const float4*)(x + i);
  float4 a = s4[0], b = s4[1], c = s4[2], d = s4[3];
  *(u16x8*)(xbf + i)     = pack8(a, b);
  *(u16x8*)(xbf + i + 8) = pack8(c, d);
}

// ---------------------------------------------------------------------------
// Phase 1: persistent LSTM v10 — store-ack OFF the chain.
// Grid = 128 WGs x 256 thr (4 waves). WG (g,cw): rows [g*16,+16), h-cols
// [cw*64,+64). Each wave owns 16 h-cols, all 4 gates; in-register update.
//
// Per-step tail (end of step s, preparing s+1), per thread, ONE asm block:
//   issue 8 poll loads (tags s+1, parity (s+1)&1, peer blocks, sc0 sc1)
//   issue 1 x load (x[s+1], plain)
//   THEN  issue 2 publish stores (xch dwordx4 sc0 sc1 + Yd dwordx4 plain)
//   s_waitcnt vmcnt(2)   <- in-order: 9 loads retired, 2 stores MAY float
// The MALL store-ack (the ~2us every prior round paid via __syncthreads
// drain (R5-R10) or store-before-load vmcnt(0) (R11)) now retires in the
// background. Respins use vmcnt(0) (stores already retired, issued earlier).
// Barriers: 2x raw lgkmcnt-only per step (As-tile WAR + hb publish ready).
// WAR safety across parity reuse is unchanged: my store of tags s+1 into
// P((s+1)&1) happens after I detected tags s from ALL peers, which proves
// their (vmcnt-waited) reads of tags s-1 from P((s+1)&1) completed.
// Tags 1..1023; prep re-zeros both parities each call (replay-safe).
// ---------------------------------------------------------------------------
__launch_bounds__(256, 1)
__global__ void lstm_persist9(const u16* __restrict__ xbf,
                              const u16* __restrict__ Whh_bf,
                              const u16* __restrict__ Wih_bf,
                              const float* __restrict__ bsum,
                              float* __restrict__ Yd,
                              uint32_t* __restrict__ xch32) {
  __shared__ u16      As[16][648];    // 16 x 640 bf16 A-tile (+pad)
  __shared__ uint32_t hb[16][68];     // tagged h block (publish coalescing)

  const int tid  = threadIdx.x;
  const int lane = tid & 63;
  const int wv   = tid >> 6;          // wave 0..3
  const int bid  = blockIdx.x;
  const int g    = bid & 15;          // batch group
  const int cw   = bid >> 4;          // col-WG 0..7
  const int br0  = g * 16;

  const int cl  = lane & 15;
  const int ko  = (lane >> 4) * 8;
  const int jcl = wv * 16 + cl;       // local col 0..63
  const int jb  = cw * 64 + jcl;      // global h col this lane owns

  // ---- persistent weight fragments: 4 gates x 20 kt ----
  bf16x8 wf[4][20];
#pragma unroll
  for (int gt = 0; gt < 4; ++gt) {
    const size_t j0 = (size_t)(gt * H_ + jb);
#pragma unroll
    for (int kt = 0; kt < 16; ++kt)
      wf[gt][kt] = *(const bf16x8*)(Whh_bf + j0 * H_ + kt * 32 + ko);
#pragma unroll
    for (int kt = 0; kt < 4; ++kt)
      wf[gt][16 + kt] = *(const bf16x8*)(Wih_bf + j0 * D_ + kt * 32 + ko);
  }
#pragma unroll
  for (int gt = 0; gt < 4; ++gt)
#pragma unroll
    for (int kt = 0; kt < 20; ++kt)
      asm volatile("" : "+v"(wf[gt][kt]));

  // ---- per-lane cell state: 4 rows x col jb ----
  const int row0 = (lane >> 4) * 4;
  float cst[4] = {0.f, 0.f, 0.f, 0.f};
  const float bi  = bsum[jb];
  const float bff = bsum[H_ + jb];
  const float bgg = bsum[2 * H_ + jb];
  const float boo = bsum[3 * H_ + jb];

  // poll/stage/publish maps
  const int pcw   = tid >> 5;         // cw-block this thread polls (uniform)
  const int pj    = tid & 31;         // 32 threads per block, 128 B each
  const int prw   = pj >> 1;          // row within block
  const int colh  = (pj & 1) * 32;    // col half (u32 units)
  const int pr2   = tid >> 4;         // publish row
  const int pc4   = (tid & 15) * 4;   // publish col base (u32 units)
  const u16* xrow = xbf + (size_t)(br0 + (tid >> 4)) * T_ * D_ + (tid & 15) * 8;

  // ---- prologue: stage zeros (h) + x(0) ----
  {
    u16x8 z = {};
#pragma unroll
    for (int i = 0; i < 4; ++i)
      *(u16x8*)&As[prw][pcw * 64 + colh + i * 8] = z;
    *(u16x8*)&As[tid >> 4][512 + (tid & 15) * 8] = *(const u16x8*)xrow;
  }
  BAR_LDS();

  for (int s = 0; s < T_ - 1; ++s) {
    // ---- MFMA: M=16, N=16 x 4 gates, K=640 ----
    f32x4 a0 = {}, a1 = {}, a2 = {}, a3 = {};
#pragma unroll
    for (int kt = 0; kt < 20; ++kt) {
      bf16x8 a = *(const bf16x8*)&As[cl][kt * 32 + ko];
      a0 = __builtin_amdgcn_mfma_f32_16x16x32_bf16(a, wf[0][kt], a0, 0, 0, 0);
      a1 = __builtin_amdgcn_mfma_f32_16x16x32_bf16(a, wf[1][kt], a1, 0, 0, 0);
      a2 = __builtin_amdgcn_mfma_f32_16x16x32_bf16(a, wf[2][kt], a2, 0, 0, 0);
      a3 = __builtin_amdgcn_mfma_f32_16x16x32_bf16(a, wf[3][kt], a3, 0, 0, 0);
    }

    // ---- in-register LSTM update -> tagged words into LDS hb ----
    {
      const uint32_t tag = (uint32_t)(s + 1);
#pragma unroll
      for (int r = 0; r < 4; ++r) {
        const float gi = a0[r] + bi;
        const float gf = a1[r] + bff;
        const float gg = a2[r] + bgg;
        const float go = a3[r] + boo;
        cst[r] = fast_sig(gf) * cst[r] + fast_sig(gi) * fast_tanh(gg);
        const float h = fast_sig(go) * fast_tanh(cst[r]);
        hb[row0 + r][jcl] = ((uint32_t)f2bf(h) << 16) | tag;
      }
    }
    BAR_LDS();   // B2: hb ready for publish readers; all As reads (MFMA) done

    // ---- gather publish data ----
    u32x4 pub = *(const u32x4*)&hb[pr2][pc4];
    u32x4 yv;
#pragma unroll
    for (int j = 0; j < 4; ++j) yv[j] = pub[j] & 0xFFFF0000u;   // bf16-prec h
    float* ydst = Yd + ((size_t)(br0 + pr2) * T_ + (s + 1)) * H_ + cw * 64 + pc4;

    if (s < T_ - 2) {
      const size_t pari = (size_t)((s + 1) & 1);
      const char* nb   = (const char*)xch32 + (((pari * NG_ + g) * NCW_ + pcw) << 12) + pj * 128;
      char*       xdst = (char*)xch32 + (((pari * NG_ + g) * NCW_ + cw) << 12) + tid * 16;
      const u16*  xaddr = xrow + (size_t)(s + 1) * D_;
      const uint32_t want = (uint32_t)(s + 1);
      u32x4 r0, r1, r2, r3, r4, r5, r6, r7, xa;
      // LOADS FIRST, stores second: vmcnt(2) completes the 9 loads while the
      // 2 publish stores retire in the background (in-order vmcnt).
      asm volatile(
        "global_load_dwordx4 %0, %9, off sc0 sc1\n\t"
        "global_load_dwordx4 %1, %9, off offset:16 sc0 sc1\n\t"
        "global_load_dwordx4 %2, %9, off offset:32 sc0 sc1\n\t"
        "global_load_dwordx4 %3, %9, off offset:48 sc0 sc1\n\t"
        "global_load_dwordx4 %4, %9, off offset:64 sc0 sc1\n\t"
        "global_load_dwordx4 %5, %9, off offset:80 sc0 sc1\n\t"
        "global_load_dwordx4 %6, %9, off offset:96 sc0 sc1\n\t"
        "global_load_dwordx4 %7, %9, off offset:112 sc0 sc1\n\t"
        "global_load_dwordx4 %8, %10, off\n\t"
        "global_store_dwordx4 %11, %13, off sc0 sc1\n\t"
        "global_store_dwordx4 %12, %14, off\n\t"
        "s_waitcnt vmcnt(2)"
        : "=&v"(r0), "=&v"(r1), "=&v"(r2), "=&v"(r3),
          "=&v"(r4), "=&v"(r5), "=&v"(r6), "=&v"(r7), "=&v"(xa)
        : "v"(nb), "v"(xaddr), "v"(xdst), "v"(ydst), "v"(pub), "v"(yv)
        : "memory");
      bool ok = true;
#pragma unroll
      for (int i = 0; i < 4; ++i) {
        ok = ok && ((r0[i] & 0xFFFFu) == want) && ((r1[i] & 0xFFFFu) == want)
                && ((r2[i] & 0xFFFFu) == want) && ((r3[i] & 0xFFFFu) == want)
                && ((r4[i] & 0xFFFFu) == want) && ((r5[i] & 0xFFFFu) == want)
                && ((r6[i] & 0xFFFFu) == want) && ((r7[i] & 0xFFFFu) == want);
      }
      while (!ok) {
        asm volatile(
          "global_load_dwordx4 %0, %8, off sc0 sc1\n\t"
          "global_load_dwordx4 %1, %8, off offset:16 sc0 sc1\n\t"
          "global_load_dwordx4 %2, %8, off offset:32 sc0 sc1\n\t"
          "global_load_dwordx4 %3, %8, off offset:48 sc0 sc1\n\t"
          "global_load_dwordx4 %4, %8, off offset:64 sc0 sc1\n\t"
          "global_load_dwordx4 %5, %8, off offset:80 sc0 sc1\n\t"
          "global_load_dwordx4 %6, %8, off offset:96 sc0 sc1\n\t"
          "global_load_dwordx4 %7, %8, off offset:112 sc0 sc1\n\t"
          "s_waitcnt vmcnt(0)"
          : "=&v"(r0), "=&v"(r1), "=&v"(r2), "=&v"(r3),
            "=&v"(r4), "=&v"(r5), "=&v"(r6), "=&v"(r7)
          : "v"(nb) : "memory");
        ok = true;
#pragma unroll
        for (int i = 0; i < 4; ++i) {
          ok = ok && ((r0[i] & 0xFFFFu) == want) && ((r1[i] & 0xFFFFu) == want)
                  && ((r2[i] & 0xFFFFu) == want) && ((r3[i] & 0xFFFFu) == want)
                  && ((r4[i] & 0xFFFFu) == want) && ((r5[i] & 0xFFFFu) == want)
                  && ((r6[i] & 0xFFFFu) == want) && ((r7[i] & 0xFFFFu) == want);
        }
      }
      // ---- stage h-part + x-part for step s+1 ----
      u16x8 d0, d1, d2, d3;
#pragma unroll
      for (int i = 0; i < 4; ++i) {
        d0[i] = (u16)(r0[i] >> 16); d0[4 + i] = (u16)(r1[i] >> 16);
        d1[i] = (u16)(r2[i] >> 16); d1[4 + i] = (u16)(r3[i] >> 16);
        d2[i] = (u16)(r4[i] >> 16); d2[4 + i] = (u16)(r5[i] >> 16);
        d3[i] = (u16)(r6[i] >> 16); d3[4 + i] = (u16)(r7[i] >> 16);
      }
      const int cb = pcw * 64 + colh;
      *(u16x8*)&As[prw][cb]      = d0;
      *(u16x8*)&As[prw][cb + 8]  = d1;
      *(u16x8*)&As[prw][cb + 16] = d2;
      *(u16x8*)&As[prw][cb + 24] = d3;
      *(u16x8*)&As[tid >> 4][512 + (tid & 15) * 8] = __builtin_bit_cast(u16x8, xa);
      BAR_LDS();   // B1: staging done -> next MFMA
    } else {
      // last step: only the Yd write matters (kernel end drains it)
      asm volatile("global_store_dwordx4 %0, %1, off"
                   :: "v"(ydst), "v"(yv) : "memory");
    }
  }
}

// ---------------------------------------------------------------------------
// Phase 2 (fused, v2 — proven R5/R7): all 4 Euler steps; 64 rows x 512 cols
// per WG. 8 waves, 1x8: each wave M=64 (4 m-frags), N=64 (4 n-frags).
// Y fp32 in regs; A-tile bf16 in LDS; B weights loaded DIRECT from global
// (L2-resident) inside the cc-loop (reg double-buffer spilled in R6 — don't).
// ---------------------------------------------------------------------------
__launch_bounds__(512)
__global__ void ode_fused2(const float* __restrict__ tptr,
                           const u16* __restrict__ w1y,
                           const u16* __restrict__ w2v,
                           const float* __restrict__ b1,
                           const float* __restrict__ b2,
                           const float* __restrict__ w1s,
                           float* __restrict__ Yd) {
  __shared__ u16 At[64][520];

  const int tid  = threadIdx.x;
  const int lane = tid & 63;
  const int wv   = tid >> 6;          // 0..7
  const int n0w  = wv * 64;
  const size_t m0 = (size_t)blockIdx.x * 64;
  const int cl = lane & 15;
  const int rq = (lane >> 4) * 4;
  const int ko = (lane >> 4) * 8;

  float b1v[4], b2v[4], w1sv[4];
#pragma unroll
  for (int nf = 0; nf < 4; ++nf) {
    const int cg = n0w + nf * 16 + cl;
    b1v[nf] = b1[cg]; b2v[nf] = b2[cg]; w1sv[nf] = w1s[cg];
  }
  float tv[4][4];
#pragma unroll
  for (int mf = 0; mf < 4; ++mf)
#pragma unroll
    for (int r = 0; r < 4; ++r)
      tv[mf][r] = 0.25f * tptr[m0 + mf * 16 + rq + r];

  f32x4 Y[4][4];
#pragma unroll
  for (int mf = 0; mf < 4; ++mf)
#pragma unroll
    for (int nf = 0; nf < 4; ++nf)
#pragma unroll
      for (int r = 0; r < 4; ++r)
        Y[mf][nf][r] = Yd[(m0 + mf * 16 + rq + r) * 512 + n0w + nf * 16 + cl];

#define WRITE_AT(EXPR)                                                        \
  do {                                                                        \
    _Pragma("unroll") for (int mf = 0; mf < 4; ++mf)                          \
    _Pragma("unroll") for (int nf = 0; nf < 4; ++nf)                          \
    _Pragma("unroll") for (int r = 0; r < 4; ++r)                             \
      At[mf * 16 + rq + r][n0w + nf * 16 + cl] = f2bf(EXPR);                  \
  } while (0)

#define GEMM_DIRECT(WPTR, ACC)                                                \
  do {                                                                        \
    _Pragma("unroll 2") for (int cc = 0; cc < 16; ++cc) {                     \
      bf16x8 bfv[4], af[4];                                                   \
      _Pragma("unroll") for (int nf = 0; nf < 4; ++nf)                        \
        bfv[nf] = *(const bf16x8*)((WPTR) + (size_t)(n0w + nf * 16 + cl) * 512\
                                   + cc * 32 + ko);                           \
      _Pragma("unroll") for (int mf = 0; mf < 4; ++mf)                        \
        af[mf] = *(const bf16x8*)&At[mf * 16 + cl][cc * 32 + ko];             \
      _Pragma("unroll") for (int mf = 0; mf < 4; ++mf)                        \
      _Pragma("unroll") for (int nf = 0; nf < 4; ++nf)                        \
        ACC[mf][nf] = __builtin_amdgcn_mfma_f32_16x16x32_bf16(                \
            af[mf], bfv[nf], ACC[mf][nf], 0, 0, 0);                           \
    }                                                                         \
  } while (0)

  WRITE_AT(Y[mf][nf][r]);
  __syncthreads();

#pragma unroll 1
  for (int k = 0; k < 4; ++k) {
    const float sk = 0.25f * k;
    f32x4 acc[4][4] = {};
    GEMM_DIRECT(w1y, acc);
    __syncthreads();
    WRITE_AT(fast_tanh(acc[mf][nf][r] + b1v[nf] + sk * w1sv[nf]));
    __syncthreads();
    f32x4 acc2[4][4] = {};
    GEMM_DIRECT(w2v, acc2);
    __syncthreads();
#pragma unroll
    for (int mf = 0; mf < 4; ++mf)
#pragma unroll
      for (int nf = 0; nf < 4; ++nf)
#pragma unroll
        for (int r = 0; r < 4; ++r)
          Y[mf][nf][r] += tv[mf][r] * (acc2[mf][nf][r] + b2v[nf]);
    if (k < 3) {
      WRITE_AT(Y[mf][nf][r]);
      __syncthreads();
    }
  }
#undef GEMM_DIRECT
#undef WRITE_AT

#pragma unroll
  for (int mf = 0; mf < 4; ++mf)
#pragma unroll
    for (int nf = 0; nf < 4; ++nf)
#pragma unroll
      for (int r = 0; r < 4; ++r)
        Yd[(m0 + mf * 16 + rq + r) * 512 + n0w + nf * 16 + cl] = Y[mf][nf][r];
}

// ---------------------------------------------------------------------------
extern "C" void kernel_launch(void* const* d_in, const int* in_sizes, int n_in,
                              void* d_out, int out_size, void* d_ws, size_t ws_size,
                              hipStream_t stream) {
  const float* x    = (const float*)d_in[0];
  const float* t    = (const float*)d_in[1];
  const float* W_ih = (const float*)d_in[2];
  const float* W_hh = (const float*)d_in[3];
  const float* b_ih = (const float*)d_in[4];
  const float* b_hh = (const float*)d_in[5];
  const float* w1   = (const float*)d_in[6];
  const float* b1   = (const float*)d_in[7];
  const float* w2   = (const float*)d_in[8];
  const float* b2   = (const float*)d_in[9];
  float* Yd = (float*)d_out;   // (B,T,H) fp32; h history and ODE state

  char* ws = (char*)d_ws;
  size_t off = 0;
  auto alloc = [&](size_t bytes) {
    void* p = ws + off;
    off += (bytes + 255) & ~(size_t)255;
    return p;
  };
  u16*      Whh_bf = (u16*)alloc((size_t)G4_ * H_ * 2);          //   2 MB
  u16*      Wih_bf = (u16*)alloc((size_t)G4_ * D_ * 2);          // 512 KB
  u16*      w1y_bf = (u16*)alloc((size_t)H_ * H_ * 2);           // 512 KB
  u16*      w2_bf  = (u16*)alloc((size_t)H_ * H_ * 2);           // 512 KB
  float*    w1s    = (float*)alloc(H_ * 4);
  float*    bsum   = (float*)alloc(G4_ * 4);
  uint32_t* xch32  = (uint32_t*)alloc((size_t)2 * B_ * H_ * 4);  // 1 MB
  u16*      xbf    = (u16*)alloc((size_t)BT_ * D_ * 2);          // 64 MB

  prep_kernel<<<4096, 256, 0, stream>>>(W_hh, W_ih, w1, w2, b_ih, b_hh,
                                        Whh_bf, Wih_bf, w1y_bf, w2_bf, w1s, bsum,
                                        xch32, Yd);
  xconv_kernel<<<8192, 256, 0, stream>>>(x, xbf);

  // Phase 1: persistent LSTM (128 WGs x 256 thr)
  lstm_persist9<<<dim3(NG_ * NCW_), 256, 0, stream>>>(xbf, Whh_bf, Wih_bf, bsum, Yd, xch32);

  // Phase 2: fused 4-step Euler ODE over all B*T rows
  ode_fused2<<<dim3(BT_ / 64), 512, 0, stream>>>(t, w1y_bf, w2_bf, b1, b2, w1s, Yd);
}

// Round 13
// 8627.799 us; speedup vs baseline: 1.2094x; 1.2094x over previous
//
#include <hip/hip_runtime.h>
#include <stdint.h>

// Problem dims (fixed)
#define B_  256
#define T_  1024
#define D_  128
#define H_  512
#define G4_ 2048            // 4*H
#define BT_ (B_ * T_)

// Persistent-LSTM partitioning: 16 batch groups x 16 col groups = 256 WGs
#define NG_ 16              // batch groups (16 rows each)
#define NC_ 16              // col groups (32 h-cols each)

typedef unsigned short u16;
typedef __attribute__((ext_vector_type(8))) short    bf16x8;  // 8 bf16 in 4 VGPRs
typedef __attribute__((ext_vector_type(8))) u16      u16x8;
typedef __attribute__((ext_vector_type(4))) float    f32x4;
typedef __attribute__((ext_vector_type(4))) uint32_t u32x4;

static __device__ __forceinline__ u16 f2bf(float f) {
  uint32_t u = __builtin_bit_cast(uint32_t, f);
  u += 0x7FFFu + ((u >> 16) & 1u);   // RNE
  return (u16)(u >> 16);
}

static __device__ __forceinline__ u16x8 pack8(float4 a, float4 b) {
  u16x8 p;
  p[0] = f2bf(a.x); p[1] = f2bf(a.y); p[2] = f2bf(a.z); p[3] = f2bf(a.w);
  p[4] = f2bf(b.x); p[5] = f2bf(b.y); p[6] = f2bf(b.z); p[7] = f2bf(b.w);
  return p;
}

static __device__ __forceinline__ float fast_sig(float x) {
  return 1.f / (1.f + __expf(-x));
}
static __device__ __forceinline__ float fast_tanh(float x) {
  return 1.f - 2.f / (__expf(2.f * x) + 1.f);
}

// ---------------------------------------------------------------------------
// prep: bf16 weight copies, bias sum, zero exchange buffer and out[:,0,:]
// ---------------------------------------------------------------------------
__global__ void prep_kernel(const float* __restrict__ Whh, const float* __restrict__ Wih,
                            const float* __restrict__ w1,  const float* __restrict__ w2,
                            const float* __restrict__ b_ih, const float* __restrict__ b_hh,
                            u16* __restrict__ Whh_bf, u16* __restrict__ Wih_bf,
                            u16* __restrict__ w1y_bf, u16* __restrict__ w2_bf,
                            float* __restrict__ w1s, float* __restrict__ bsum,
                            uint32_t* __restrict__ xch32, float* __restrict__ Yd) {
  const int idx = blockIdx.x * blockDim.x + threadIdx.x;
  if (idx < G4_ * H_) Whh_bf[idx] = f2bf(Whh[idx]);          // 1,048,576
  if (idx < G4_ * D_) Wih_bf[idx] = f2bf(Wih[idx]);          // 262,144
  if (idx < H_ * H_) {                                       // 262,144
    const int n = idx >> 9, k = idx & 511;
    w1y_bf[idx] = f2bf(w1[n * 513 + 1 + k]);                 // w1[:,1:]
    w2_bf[idx]  = f2bf(w2[idx]);
  }
  if (idx < H_)  w1s[idx]  = w1[idx * 513];                  // w1[:,0]
  if (idx < G4_) bsum[idx] = b_ih[idx] + b_hh[idx];
  if (idx < 2 * B_ * H_) xch32[idx] = 0;                     // 262,144 (tag 0)
  if (idx < B_ * H_) {                                       // 131,072
    const int b = idx >> 9, h = idx & 511;
    Yd[(size_t)b * T_ * H_ + h] = 0.f;                       // out[b,0,:] = h_0 = 0
  }
}

// x fp32 -> bf16 pre-conversion (33.5M elems; 16 per thread)
__global__ void xconv_kernel(const float* __restrict__ x, u16* __restrict__ xbf) {
  const size_t i = ((size_t)blockIdx.x * blockDim.x + threadIdx.x) * 16;
  const float4* s4 = (const float4*)(x + i);
  float4 a = s4[0], b = s4[1], c = s4[2], d = s4[3];
  *(u16x8*)(xbf + i)     = pack8(a, b);
  *(u16x8*)(xbf + i + 8) = pack8(c, d);
}

// ---------------------------------------------------------------------------
// Phase 1: persistent LSTM — EXACT revert to R7's lstm_persist4 (best: 4.31ms).
// Grid = 256 WGs x 256 thr (4 waves). WG (g,c): rows [g*16,+16), h-cols
// [c*32,+32). Wave gw = one gate (160 regs/lane weights).
// Exchange: self-validating tagged words ((bf16(h)<<16)|step per u32, u64
// relaxed agent-scope stores -> MALL). Consumers poll their own 128 B with
// 8x coalesced dwordx4 sc0 sc1 — detection and payload arrive together.
// Parity double-buffer; poll success at step s transitively proves peers
// finished reading parity (s&1). Tags 1..1023; prep re-zeros. x pre-converted
// bf16 and register-prefetched one step ahead.
// ---------------------------------------------------------------------------
__launch_bounds__(256, 1)
__global__ void lstm_persist4(const u16* __restrict__ xbf,
                              const u16* __restrict__ Whh_bf,
                              const u16* __restrict__ Wih_bf,
                              const float* __restrict__ bsum,
                              float* __restrict__ Yd,
                              uint32_t* __restrict__ xch32) {
  __shared__ u16   As[16][648];       // 16 x 640 bf16 A-tile (+pad)
  __shared__ float Gs[4][16][34];     // gate exchange

  const int tid  = threadIdx.x;
  const int lane = tid & 63;
  const int gw   = tid >> 6;          // gate 0..3
  const int w    = blockIdx.x;
  const int g    = (w & 7) * 2 + (w >> 7);   // batch group (XCD-affine)
  const int c    = (w >> 3) & 15;            // col group
  const int br0  = g * 16;
  const int hc0  = c * 32;

  const int cl = lane & 15;
  const int ko = (lane >> 4) * 8;

  // ---- persistent weight fragments: gate gw, cols hc0..hc0+32 ----
  bf16x8 wf0[20], wf1[20];
  {
    const int j0 = gw * H_ + hc0 + cl;
#pragma unroll
    for (int kt = 0; kt < 16; ++kt) {
      wf0[kt] = *(const bf16x8*)(Whh_bf + (size_t)j0 * H_ + kt * 32 + ko);
      wf1[kt] = *(const bf16x8*)(Whh_bf + (size_t)(j0 + 16) * H_ + kt * 32 + ko);
    }
#pragma unroll
    for (int kt = 0; kt < 4; ++kt) {
      wf0[16 + kt] = *(const bf16x8*)(Wih_bf + (size_t)j0 * D_ + kt * 32 + ko);
      wf1[16 + kt] = *(const bf16x8*)(Wih_bf + (size_t)(j0 + 16) * D_ + kt * 32 + ko);
    }
  }
  asm volatile("" ::: "memory");

  // ---- per-thread cell state: row er, cols (jb, jb+1) ----
  const int er = tid >> 4;            // 0..15
  const int ec = (tid & 15) * 2;      // 0..30
  const int jb = hc0 + ec;
  float c0 = 0.f, c1 = 0.f;
  const float bi0 = bsum[jb],            bi1 = bsum[jb + 1];
  const float bf0 = bsum[H_ + jb],       bf1 = bsum[H_ + jb + 1];
  const float bg0 = bsum[2 * H_ + jb],   bg1 = bsum[2 * H_ + jb + 1];
  const float bo0 = bsum[3 * H_ + jb],   bo1 = bsum[3 * H_ + jb + 1];

  const int xr   = tid & 15,  xk   = tid >> 4;   // x-stage map
  const int prow = tid >> 4;                     // poll row 0..15
  const int pcb  = (tid & 15) * 32;              // poll col base (u32 words)

  // x register prefetch (one step ahead)
  const u16* xrow = xbf + (size_t)(br0 + xr) * T_ * D_ + xk * 8;
  u16x8 xa = *(const u16x8*)(xrow);   // step 0

  for (int s = 0; s < T_ - 1; ++s) {
    // ---- stage x-part (cols 512..639) from prefetch regs; issue next ----
    *(u16x8*)&As[xr][512 + xk * 8] = xa;
    xa = *(const u16x8*)(xrow + (size_t)(s + 1) * D_);   // covered by poll+MFMA

    // ---- stage h-part (cols 0..511): coalesced tagged poll ----
    if (s == 0) {
      u16x8 z = {};
#pragma unroll
      for (int i = 0; i < 4; ++i) *(u16x8*)&As[prow][pcb + i * 8] = z;
    } else {
      const char* base = (const char*)(xch32 + (((size_t)(s & 1) * NG_ + g) << 13)) + tid * 128;
      const uint32_t want = (uint32_t)s;
      u32x4 r0, r1, r2, r3, r4, r5, r6, r7;
      bool ok;
      do {
        asm volatile(
          "global_load_dwordx4 %0, %8, off sc0 sc1\n\t"
          "global_load_dwordx4 %1, %8, off offset:16 sc0 sc1\n\t"
          "global_load_dwordx4 %2, %8, off offset:32 sc0 sc1\n\t"
          "global_load_dwordx4 %3, %8, off offset:48 sc0 sc1\n\t"
          "global_load_dwordx4 %4, %8, off offset:64 sc0 sc1\n\t"
          "global_load_dwordx4 %5, %8, off offset:80 sc0 sc1\n\t"
          "global_load_dwordx4 %6, %8, off offset:96 sc0 sc1\n\t"
          "global_load_dwordx4 %7, %8, off offset:112 sc0 sc1\n\t"
          "s_waitcnt vmcnt(0)"
          : "=&v"(r0), "=&v"(r1), "=&v"(r2), "=&v"(r3),
            "=&v"(r4), "=&v"(r5), "=&v"(r6), "=&v"(r7)
          : "v"(base) : "memory");
        ok = true;
#pragma unroll
        for (int i = 0; i < 4; ++i) {
          ok = ok && ((r0[i] & 0xFFFFu) == want) && ((r1[i] & 0xFFFFu) == want)
                  && ((r2[i] & 0xFFFFu) == want) && ((r3[i] & 0xFFFFu) == want)
                  && ((r4[i] & 0xFFFFu) == want) && ((r5[i] & 0xFFFFu) == want)
                  && ((r6[i] & 0xFFFFu) == want) && ((r7[i] & 0xFFFFu) == want);
        }
      } while (!ok);
      u16x8 d0, d1, d2, d3;
#pragma unroll
      for (int i = 0; i < 4; ++i) {
        d0[i] = (u16)(r0[i] >> 16); d0[4 + i] = (u16)(r1[i] >> 16);
        d1[i] = (u16)(r2[i] >> 16); d1[4 + i] = (u16)(r3[i] >> 16);
        d2[i] = (u16)(r4[i] >> 16); d2[4 + i] = (u16)(r5[i] >> 16);
        d3[i] = (u16)(r6[i] >> 16); d3[4 + i] = (u16)(r7[i] >> 16);
      }
      *(u16x8*)&As[prow][pcb]      = d0;
      *(u16x8*)&As[prow][pcb + 8]  = d1;
      *(u16x8*)&As[prow][pcb + 16] = d2;
      *(u16x8*)&As[prow][pcb + 24] = d3;
    }
    __syncthreads();                  // barrier 1: stage -> MFMA

    // ---- MFMA: M=16, N=32 (2 frags), K=640 ----
    f32x4 acc0 = {}, acc1 = {};
#pragma unroll
    for (int kt = 0; kt < 20; ++kt) {
      bf16x8 a = *(const bf16x8*)&As[cl][kt * 32 + ko];
      acc0 = __builtin_amdgcn_mfma_f32_16x16x32_bf16(a, wf0[kt], acc0, 0, 0, 0);
      acc1 = __builtin_amdgcn_mfma_f32_16x16x32_bf16(a, wf1[kt], acc1, 0, 0, 0);
    }

    // ---- gate exchange ----
    {
      const int rr = (lane >> 4) * 4;
#pragma unroll
      for (int r = 0; r < 4; ++r) {
        Gs[gw][rr + r][cl]      = acc0[r];
        Gs[gw][rr + r][16 + cl] = acc1[r];
      }
    }
    __syncthreads();                  // barrier 2: exchange -> update

    // ---- cell update + tagged h publication ----
    {
      const float2 gi = *(const float2*)&Gs[0][er][ec];
      const float2 gf = *(const float2*)&Gs[1][er][ec];
      const float2 gg = *(const float2*)&Gs[2][er][ec];
      const float2 go = *(const float2*)&Gs[3][er][ec];
      c0 = fast_sig(gf.x + bf0) * c0 + fast_sig(gi.x + bi0) * fast_tanh(gg.x + bg0);
      c1 = fast_sig(gf.y + bf1) * c1 + fast_sig(gi.y + bi1) * fast_tanh(gg.y + bg1);
      const float h0v = fast_sig(go.x + bo0) * fast_tanh(c0);
      const float h1v = fast_sig(go.y + bo1) * fast_tanh(c1);
      const uint32_t tag = (uint32_t)(s + 1);
      const uint32_t lo  = ((uint32_t)f2bf(h0v) << 16) | tag;
      const uint32_t hi  = ((uint32_t)f2bf(h1v) << 16) | tag;
      __hip_atomic_store(
          (uint64_t*)(xch32 + (((size_t)((s + 1) & 1) * NG_ + g) << 13) + (er << 9) + jb),
          ((uint64_t)hi << 32) | lo, __ATOMIC_RELAXED, __HIP_MEMORY_SCOPE_AGENT);
      float2 hv; hv.x = h0v; hv.y = h1v;
      *(float2*)(Yd + ((size_t)(br0 + er) * T_ + (s + 1)) * H_ + jb) = hv;
    }
    // no loop-end barrier: poll success next step transitively orders peers
  }
}

// ---------------------------------------------------------------------------
// Phase 2 (fused, v4): all 4 Euler steps; 64 rows x 512 cols per WG.
// 8 waves 1x8: each wave M=64 (4 m-frags), N=64 (4 n-frags). Y fp32 in regs;
// A-tile bf16 in LDS; B read from global (L2-resident) with a 2-slot
// register double-buffer (8 loads in flight). __launch_bounds__(512, 2)
// gives a 256-VGPR budget — R6's identical pipeline spilled only because the
// default bound capped regs at 128 (Y64+acc64+bv32+af16 > 128).
// ---------------------------------------------------------------------------
__launch_bounds__(512, 2)
__global__ void ode_fused4(const float* __restrict__ tptr,
                           const u16* __restrict__ w1y,
                           const u16* __restrict__ w2v,
                           const float* __restrict__ b1,
                           const float* __restrict__ b2,
                           const float* __restrict__ w1s,
                           float* __restrict__ Yd) {
  __shared__ u16 At[64][520];

  const int tid  = threadIdx.x;
  const int lane = tid & 63;
  const int wv   = tid >> 6;          // 0..7
  const int n0w  = wv * 64;
  const size_t m0 = (size_t)blockIdx.x * 64;
  const int cl = lane & 15;
  const int rq = (lane >> 4) * 4;
  const int ko = (lane >> 4) * 8;

  float b1v[4], b2v[4], w1sv[4];
#pragma unroll
  for (int nf = 0; nf < 4; ++nf) {
    const int cg = n0w + nf * 16 + cl;
    b1v[nf] = b1[cg]; b2v[nf] = b2[cg]; w1sv[nf] = w1s[cg];
  }
  float tv[4][4];
#pragma unroll
  for (int mf = 0; mf < 4; ++mf)
#pragma unroll
    for (int r = 0; r < 4; ++r)
      tv[mf][r] = 0.25f * tptr[m0 + mf * 16 + rq + r];

  // load Y (fp32) into registers (C-frag layout, wave's 64-col band)
  f32x4 Y[4][4];
#pragma unroll
  for (int mf = 0; mf < 4; ++mf)
#pragma unroll
    for (int nf = 0; nf < 4; ++nf)
#pragma unroll
      for (int r = 0; r < 4; ++r)
        Y[mf][nf][r] = Yd[(m0 + mf * 16 + rq + r) * 512 + n0w + nf * 16 + cl];

#define WRITE_AT(EXPR)                                                        \
  do {                                                                        \
    _Pragma("unroll") for (int mf = 0; mf < 4; ++mf)                          \
    _Pragma("unroll") for (int nf = 0; nf < 4; ++nf)                          \
    _Pragma("unroll") for (int r = 0; r < 4; ++r)                             \
      At[mf * 16 + rq + r][n0w + nf * 16 + cl] = f2bf(EXPR);                  \
  } while (0)

#define GEMM_PIPE(WPTR, ACC)                                                  \
  do {                                                                        \
    const u16* wbase = (WPTR) + (size_t)(n0w + cl) * 512 + ko;                \
    bf16x8 bv[2][4];                                                          \
    _Pragma("unroll") for (int nf = 0; nf < 4; ++nf) {                        \
      bv[0][nf] = *(const bf16x8*)(wbase + nf * 16 * 512);                    \
      bv[1][nf] = *(const bf16x8*)(wbase + nf * 16 * 512 + 32);               \
    }                                                                         \
    _Pragma("unroll") for (int cc = 0; cc < 16; ++cc) {                       \
      bf16x8 af[4];                                                           \
      _Pragma("unroll") for (int mf = 0; mf < 4; ++mf)                        \
        af[mf] = *(const bf16x8*)&At[mf * 16 + cl][cc * 32 + ko];             \
      _Pragma("unroll") for (int mf = 0; mf < 4; ++mf)                        \
      _Pragma("unroll") for (int nf = 0; nf < 4; ++nf)                        \
        ACC[mf][nf] = __builtin_amdgcn_mfma_f32_16x16x32_bf16(                \
            af[mf], bv[cc & 1][nf], ACC[mf][nf], 0, 0, 0);                    \
      if (cc < 14) {                                                          \
        _Pragma("unroll") for (int nf = 0; nf < 4; ++nf)                      \
          bv[cc & 1][nf] =                                                    \
              *(const bf16x8*)(wbase + nf * 16 * 512 + (cc + 2) * 32);        \
      }                                                                       \
    }                                                                         \
  } while (0)

  WRITE_AT(Y[mf][nf][r]);
  __syncthreads();

#pragma unroll 1
  for (int k = 0; k < 4; ++k) {
    const float sk = 0.25f * k;
    // ---- GEMM1: G1 = tanh(A @ w1y^T + b1 + s*w1s) ----
    f32x4 acc[4][4] = {};
    GEMM_PIPE(w1y, acc);
    __syncthreads();                  // At reads done
    WRITE_AT(fast_tanh(acc[mf][nf][r] + b1v[nf] + sk * w1sv[nf]));
    __syncthreads();
    // ---- GEMM2: Y += dt*t*(G1 @ w2^T + b2) ----
    f32x4 acc2[4][4] = {};
    GEMM_PIPE(w2v, acc2);
    __syncthreads();                  // At reads done
#pragma unroll
    for (int mf = 0; mf < 4; ++mf)
#pragma unroll
      for (int nf = 0; nf < 4; ++nf)
#pragma unroll
        for (int r = 0; r < 4; ++r)
          Y[mf][nf][r] += tv[mf][r] * (acc2[mf][nf][r] + b2v[nf]);
    if (k < 3) {
      WRITE_AT(Y[mf][nf][r]);
      __syncthreads();
    }
  }
#undef GEMM_PIPE
#undef WRITE_AT

  // write back Y (fp32)
#pragma unroll
  for (int mf = 0; mf < 4; ++mf)
#pragma unroll
    for (int nf = 0; nf < 4; ++nf)
#pragma unroll
      for (int r = 0; r < 4; ++r)
        Yd[(m0 + mf * 16 + rq + r) * 512 + n0w + nf * 16 + cl] = Y[mf][nf][r];
}

// ---------------------------------------------------------------------------
extern "C" void kernel_launch(void* const* d_in, const int* in_sizes, int n_in,
                              void* d_out, int out_size, void* d_ws, size_t ws_size,
                              hipStream_t stream) {
  const float* x    = (const float*)d_in[0];
  const float* t    = (const float*)d_in[1];
  const float* W_ih = (const float*)d_in[2];
  const float* W_hh = (const float*)d_in[3];
  const float* b_ih = (const float*)d_in[4];
  const float* b_hh = (const float*)d_in[5];
  const float* w1   = (const float*)d_in[6];
  const float* b1   = (const float*)d_in[7];
  const float* w2   = (const float*)d_in[8];
  const float* b2   = (const float*)d_in[9];
  float* Yd = (float*)d_out;   // (B,T,H) fp32; h history and ODE state

  char* ws = (char*)d_ws;
  size_t off = 0;
  auto alloc = [&](size_t bytes) {
    void* p = ws + off;
    off += (bytes + 255) & ~(size_t)255;
    return p;
  };
  u16*      Whh_bf = (u16*)alloc((size_t)G4_ * H_ * 2);          //   2 MB
  u16*      Wih_bf = (u16*)alloc((size_t)G4_ * D_ * 2);          // 512 KB
  u16*      w1y_bf = (u16*)alloc((size_t)H_ * H_ * 2);           // 512 KB
  u16*      w2_bf  = (u16*)alloc((size_t)H_ * H_ * 2);           // 512 KB
  float*    w1s    = (float*)alloc(H_ * 4);
  float*    bsum   = (float*)alloc(G4_ * 4);
  uint32_t* xch32  = (uint32_t*)alloc((size_t)2 * B_ * H_ * 4);  // 1 MB
  u16*      xbf    = (u16*)alloc((size_t)BT_ * D_ * 2);          // 64 MB

  prep_kernel<<<4096, 256, 0, stream>>>(W_hh, W_ih, w1, w2, b_ih, b_hh,
                                        Whh_bf, Wih_bf, w1y_bf, w2_bf, w1s, bsum,
                                        xch32, Yd);
  xconv_kernel<<<8192, 256, 0, stream>>>(x, xbf);

  // Phase 1: persistent LSTM (256 WGs x 256 thr = 1 WG/CU, all resident)
  lstm_persist4<<<dim3(NG_ * NC_), 256, 0, stream>>>(xbf, Whh_bf, Wih_bf, bsum, Yd, xch32);

  // Phase 2: fused 4-step Euler ODE over all B*T rows
  ode_fused4<<<dim3(BT_ / 64), 512, 0, stream>>>(t, w1y_bf, w2_bf, b1, b2, w1s, Yd);
}